// Round 7
// baseline (1254.462 us; speedup 1.0000x reference)
//
#include <hip/hip_runtime.h>

// E = 800000, D = 64, N = 50000, MLP 320 -> 256 -> 256 -> 64.
// R6: - MT=128 @ 512 threads (2x4 wave grid, 4 e-tiles/wave): halves L2
//       weight streaming per edge (was the dominant cost at 21us/pair-slot)
//     - LDS = 160 KiB exactly (Ah/Al [128][320] u16, XOR-swizzled), 1 blk/CU
//     - merged agg table [node][4][64] u16 (sumH|sumL|mulH|mulL): contiguous
//       128B writes per section (kills 8B write amplification) + read locality
//     - keeps: W1 linearity fold, perm-pack splits, setprio, CSR aggregation
//
// d_ws: T u16[N*256] | P1h/P1l u16[81920] | P2h/P2l u16[65536] | P3h/P3l u16[16384]
//       | deg int[N] | cursor int[N] | off int[N+16] | elist int[2E]

#define NNODES 50000
#define MT 128

typedef unsigned short u16;
typedef unsigned int u32;
typedef __attribute__((ext_vector_type(8))) short bf16x8;
typedef __attribute__((ext_vector_type(4))) float f32x4;

#define PSEL 0x07060302u   // result = [b.hi16, a.hi16] (a -> low half)

// swizzled H-tile address: element (m, k) of a [128][320] u16 tile
__device__ __forceinline__ void* a_ptr(u16* base, int m, int k) {
    int byte = (m * 320 + k) * 2;
    byte ^= (m & 7) << 4;
    return (char*)base + byte;
}

__device__ inline void split_rne(float x, u16& hi, u16& lo) {   // cold pack path
    unsigned u = __float_as_uint(x);
    unsigned r = (u + 0x7FFFu + ((u >> 16) & 1u)) >> 16;
    hi = (u16)r;
    float hf = __uint_as_float(r << 16);
    float l = x - hf;
    unsigned ul = __float_as_uint(l);
    unsigned rl = (ul + 0x7FFFu + ((ul >> 16) & 1u)) >> 16;
    lo = (u16)rl;
}

// hot split: hi = trunc, lo = trunc(x - hi); perm-packed
__device__ __forceinline__ void split_pack4(float v0, float v1, float v2, float v3,
                                            uint2& hw, uint2& lw) {
    u32 u0 = __float_as_uint(v0), u1 = __float_as_uint(v1);
    u32 u2 = __float_as_uint(v2), u3 = __float_as_uint(v3);
    hw.x = __builtin_amdgcn_perm(u1, u0, PSEL);
    hw.y = __builtin_amdgcn_perm(u3, u2, PSEL);
    float l0 = v0 - __uint_as_float(u0 & 0xFFFF0000u);
    float l1 = v1 - __uint_as_float(u1 & 0xFFFF0000u);
    float l2 = v2 - __uint_as_float(u2 & 0xFFFF0000u);
    float l3 = v3 - __uint_as_float(u3 & 0xFFFF0000u);
    lw.x = __builtin_amdgcn_perm(__float_as_uint(l1), __float_as_uint(l0), PSEL);
    lw.y = __builtin_amdgcn_perm(__float_as_uint(l3), __float_as_uint(l2), PSEL);
}

// ---------------------------------------------------------------- CSR build
__global__ __launch_bounds__(256) void csr_init(int* __restrict__ deg,
                                                int* __restrict__ cursor, int n) {
    int t = blockIdx.x * 256 + threadIdx.x;
    if (t < n) { deg[t] = 0; cursor[t] = 0; }
}

__global__ __launch_bounds__(256) void count_deg(const int* __restrict__ ei,
                                                 int* __restrict__ deg, int twoE) {
    int t = blockIdx.x * 256 + threadIdx.x;
    if (t < twoE) atomicAdd(&deg[ei[t]], 1);
}

// single block, 1024 threads: chunked serial + block-scan of partials
__global__ __launch_bounds__(1024) void scan_deg(const int* __restrict__ deg,
                                                 int* __restrict__ off, int n) {
    __shared__ int part[1024];
    int tid = threadIdx.x;
    int chunk = (n + 1023) / 1024;
    int lo = tid * chunk;
    int hi = lo + chunk; if (hi > n) hi = n;
    int s = 0;
    for (int i = lo; i < hi; ++i) s += deg[i];
    part[tid] = s;
    __syncthreads();
    for (int st = 1; st < 1024; st <<= 1) {
        int v = (tid >= st) ? part[tid - st] : 0;
        __syncthreads();
        part[tid] += v;
        __syncthreads();
    }
    int pre = tid ? part[tid - 1] : 0;
    for (int i = lo; i < hi; ++i) { off[i] = pre; pre += deg[i]; }
    if (tid == 1023) off[n] = pre;
}

__global__ __launch_bounds__(256) void fill_csr(const int* __restrict__ ei,
                                                const int* __restrict__ off,
                                                int* __restrict__ cursor,
                                                int* __restrict__ elist,
                                                int E) {
    int t = blockIdx.x * 256 + threadIdx.x;
    if (t >= 2 * E) return;
    int n = ei[t];
    int p = atomicAdd(&cursor[n], 1);
    elist[off[n] + p] = (t < E) ? t : t - E;
}

// one wave per node; writes merged split table T[node][4][64]:
// s=0 sumH, 1 sumL, 2 mulH, 3 mulL. 16 lanes x 8B = contiguous 128B/section.
__global__ __launch_bounds__(256) void node_aggregate(
    const float4* __restrict__ feat4, const int* __restrict__ off,
    const int* __restrict__ elist,
    u16* __restrict__ T, int nNodes) {
    int node = blockIdx.x * 4 + (threadIdx.x >> 6);
    if (node >= nNodes) return;
    int lane = threadIdx.x & 63;
    int g = lane >> 4, q = lane & 15;
    int beg = off[node], end = off[node + 1];
    float4 s = make_float4(0.f, 0.f, 0.f, 0.f);
    float4 p = make_float4(1.f, 1.f, 1.f, 1.f);
    for (int i = beg + g; i < end; i += 4) {
        float4 x = feat4[(size_t)elist[i] * 16 + q];
        s.x += x.x; s.y += x.y; s.z += x.z; s.w += x.w;
        p.x *= x.x; p.y *= x.y; p.z *= x.z; p.w *= x.w;
    }
    #pragma unroll
    for (int d = 16; d < 64; d <<= 1) {
        s.x += __shfl_xor(s.x, d); s.y += __shfl_xor(s.y, d);
        s.z += __shfl_xor(s.z, d); s.w += __shfl_xor(s.w, d);
        p.x *= __shfl_xor(p.x, d); p.y *= __shfl_xor(p.y, d);
        p.z *= __shfl_xor(p.z, d); p.w *= __shfl_xor(p.w, d);
    }
    if (g == 0) {
        uint2 hw, lw;
        size_t base = (size_t)node * 256 + q * 4;
        split_pack4(s.x, s.y, s.z, s.w, hw, lw);
        *(uint2*)&T[base]       = hw;
        *(uint2*)&T[base + 64]  = lw;
        split_pack4(p.x, p.y, p.z, p.w, hw, lw);
        *(uint2*)&T[base + 128] = hw;
        *(uint2*)&T[base + 192] = lw;
    }
}

// ---------------------------------------------------------------- W pack
// frag = (ct*KT + kt)*64 + lane; lane holds W[ct*16+(lane&15)][kt*32+(lane>>4)*8+j]
// Layer-1 fold: col k<64 -> W1[r][k] - W1[r][64+k] - W1[r][128+k]
__global__ __launch_bounds__(256) void pack_weights(
    const float* __restrict__ W1, const float* __restrict__ W2,
    const float* __restrict__ W3,
    u16* __restrict__ P1h, u16* __restrict__ P1l,
    u16* __restrict__ P2h, u16* __restrict__ P2l,
    u16* __restrict__ P3h, u16* __restrict__ P3l) {
    int t = blockIdx.x * 256 + threadIdx.x;
    const float* W; u16 *Ph, *Pl; int K, frag, fold = 0;
    if (t < 10240)        { W = W1; Ph = P1h; Pl = P1l; K = 320; frag = t; fold = 1; }
    else if (t < 18432)   { W = W2; Ph = P2h; Pl = P2l; K = 256; frag = t - 10240; }
    else if (t < 20480)   { W = W3; Ph = P3h; Pl = P3l; K = 256; frag = t - 18432; }
    else return;
    int KT = K / 32;
    int lane = frag & 63;
    int tile = frag >> 6;
    int kt = tile % KT;
    int ct = tile / KT;
    int row = ct * 16 + (lane & 15);
    int k0 = kt * 32 + (lane >> 4) * 8;
    const float* src = W + (size_t)row * K;
    u16* dh = Ph + (size_t)frag * 8;
    u16* dl = Pl + (size_t)frag * 8;
    #pragma unroll
    for (int j = 0; j < 8; ++j) {
        int k = k0 + j;
        float v = src[k];
        if (fold && k < 64) v -= src[64 + k] + src[128 + k];
        u16 h, l;
        split_rne(v, h, l);
        dh[j] = h; dl[j] = l;
    }
}

// ---------------------------------------------------------------- MFMA MLP
// 512 threads = 8 waves (wr 0..1 x wc 0..3), MT=128 edges (8 e-tiles, 4/wave).
// MFMA(A = W-frag, B = H-frag): D col(lane&15) = edge, row = 4 consecutive features.
__global__ __launch_bounds__(512, 2) void mlp_mfma(
    const float* __restrict__ feat, const int* __restrict__ ei,
    const u16* __restrict__ T,
    const u16* __restrict__ P1h, const u16* __restrict__ P1l,
    const u16* __restrict__ P2h, const u16* __restrict__ P2l,
    const u16* __restrict__ P3h, const u16* __restrict__ P3l,
    const float* __restrict__ b1, const float* __restrict__ b2,
    const float* __restrict__ b3,
    float* __restrict__ out, int E) {
    __shared__ __align__(16) u16 Ah[MT * 320];   // 80 KiB, XOR-swizzled
    __shared__ __align__(16) u16 Al[MT * 320];   // 80 KiB

    const int tid = threadIdx.x;
    const int e0 = blockIdx.x * MT;

    // ---- gather h0 = [feat | Su | Sv | Mu | Mv]
    // 5120 items = 128 edges x 5 sections x 8 octs; 10 items/thread. E%128==0.
    #pragma unroll
    for (int it = 0; it < 10; ++it) {
        int idx = tid + it * 512;
        int r = idx / 40;
        int rem = idx - r * 40;
        int sec = rem >> 3, oct = rem & 7;
        int e = e0 + r;
        int col = sec * 64 + oct * 8;
        uint4 hv, lv;
        if (sec == 0) {
            const float4* f4 = (const float4*)(feat + (size_t)e * 64 + oct * 8);
            float4 a = f4[0], b = f4[1];
            u32 u0 = __float_as_uint(a.x), u1 = __float_as_uint(a.y);
            u32 u2 = __float_as_uint(a.z), u3 = __float_as_uint(a.w);
            u32 u4 = __float_as_uint(b.x), u5 = __float_as_uint(b.y);
            u32 u6 = __float_as_uint(b.z), u7 = __float_as_uint(b.w);
            hv.x = __builtin_amdgcn_perm(u1, u0, PSEL);
            hv.y = __builtin_amdgcn_perm(u3, u2, PSEL);
            hv.z = __builtin_amdgcn_perm(u5, u4, PSEL);
            hv.w = __builtin_amdgcn_perm(u7, u6, PSEL);
            float l0 = a.x - __uint_as_float(u0 & 0xFFFF0000u);
            float l1 = a.y - __uint_as_float(u1 & 0xFFFF0000u);
            float l2 = a.z - __uint_as_float(u2 & 0xFFFF0000u);
            float l3 = a.w - __uint_as_float(u3 & 0xFFFF0000u);
            float l4 = b.x - __uint_as_float(u4 & 0xFFFF0000u);
            float l5 = b.y - __uint_as_float(u5 & 0xFFFF0000u);
            float l6 = b.z - __uint_as_float(u6 & 0xFFFF0000u);
            float l7 = b.w - __uint_as_float(u7 & 0xFFFF0000u);
            lv.x = __builtin_amdgcn_perm(__float_as_uint(l1), __float_as_uint(l0), PSEL);
            lv.y = __builtin_amdgcn_perm(__float_as_uint(l3), __float_as_uint(l2), PSEL);
            lv.z = __builtin_amdgcn_perm(__float_as_uint(l5), __float_as_uint(l4), PSEL);
            lv.w = __builtin_amdgcn_perm(__float_as_uint(l7), __float_as_uint(l6), PSEL);
        } else {
            int node = ei[(size_t)((sec & 1) ? 0 : E) + e];   // sec 1,3 -> u; 2,4 -> v
            int s = (sec <= 2) ? 0 : 2;                       // sum vs mul (hi)
            size_t base = (size_t)node * 256 + s * 64 + oct * 8;
            hv = *(const uint4*)(T + base);
            lv = *(const uint4*)(T + base + 64);
        }
        *(uint4*)a_ptr(Ah, r, col) = hv;
        *(uint4*)a_ptr(Al, r, col) = lv;
    }
    __syncthreads();

    const int lane = tid & 63;
    const int w = tid >> 6;
    const int wr = w >> 2;        // 0..1: e-tiles wr*4 + {0..3}
    const int wc = w & 3;         // 0..3: feature tiles wc*4 + {0..3}
    const int lrow = lane & 15;
    const int kgrp = (lane >> 4) * 8;

    const f32x4 zf = {0.f, 0.f, 0.f, 0.f};
    f32x4 acc[4][4];

    // ================= layer 1: K=320 (KT=10), relu
    #pragma unroll
    for (int i = 0; i < 4; ++i)
        #pragma unroll
        for (int j = 0; j < 4; ++j) acc[i][j] = zf;
    {
        const u16 *wbh[4], *wbl[4];
        #pragma unroll
        for (int j = 0; j < 4; ++j) {
            size_t off = ((size_t)(wc * 4 + j) * 10 * 64 + lane) * 8;
            wbh[j] = P1h + off; wbl[j] = P1l + off;
        }
        for (int kt = 0; kt < 10; ++kt) {
            bf16x8 hh[4], hl[4];
            #pragma unroll
            for (int i = 0; i < 4; ++i) {
                int er = (wr * 4 + i) * 16 + lrow;
                hh[i] = *(const bf16x8*)a_ptr(Ah, er, kt * 32 + kgrp);
                hl[i] = *(const bf16x8*)a_ptr(Al, er, kt * 32 + kgrp);
            }
            bf16x8 wh[4], wl[4];
            #pragma unroll
            for (int j = 0; j < 4; ++j) {
                wh[j] = *(const bf16x8*)(wbh[j] + kt * 512);
                wl[j] = *(const bf16x8*)(wbl[j] + kt * 512);
            }
            __builtin_amdgcn_s_setprio(1);
            #pragma unroll
            for (int j = 0; j < 4; ++j)
                #pragma unroll
                for (int i = 0; i < 4; ++i) {
                    acc[i][j] = __builtin_amdgcn_mfma_f32_16x16x32_bf16(wh[j], hh[i], acc[i][j], 0, 0, 0);
                    acc[i][j] = __builtin_amdgcn_mfma_f32_16x16x32_bf16(wl[j], hh[i], acc[i][j], 0, 0, 0);
                    acc[i][j] = __builtin_amdgcn_mfma_f32_16x16x32_bf16(wh[j], hl[i], acc[i][j], 0, 0, 0);
                }
            __builtin_amdgcn_s_setprio(0);
        }
    }
    __syncthreads();
    #pragma unroll
    for (int j = 0; j < 4; ++j) {
        int nb = (wc * 4 + j) * 16 + (lane >> 4) * 4;
        float4 bv = *(const float4*)&b1[nb];
        #pragma unroll
        for (int i = 0; i < 4; ++i) {
            int e = (wr * 4 + i) * 16 + lrow;
            float v0 = fmaxf(acc[i][j][0] + bv.x, 0.f);
            float v1 = fmaxf(acc[i][j][1] + bv.y, 0.f);
            float v2 = fmaxf(acc[i][j][2] + bv.z, 0.f);
            float v3 = fmaxf(acc[i][j][3] + bv.w, 0.f);
            uint2 hw, lw;
            split_pack4(v0, v1, v2, v3, hw, lw);
            *(uint2*)a_ptr(Ah, e, nb) = hw;
            *(uint2*)a_ptr(Al, e, nb) = lw;
        }
    }
    __syncthreads();

    // ================= layer 2: K=256 (KT=8), relu
    #pragma unroll
    for (int i = 0; i < 4; ++i)
        #pragma unroll
        for (int j = 0; j < 4; ++j) acc[i][j] = zf;
    {
        const u16 *wbh[4], *wbl[4];
        #pragma unroll
        for (int j = 0; j < 4; ++j) {
            size_t off = ((size_t)(wc * 4 + j) * 8 * 64 + lane) * 8;
            wbh[j] = P2h + off; wbl[j] = P2l + off;
        }
        for (int kt = 0; kt < 8; ++kt) {
            bf16x8 hh[4], hl[4];
            #pragma unroll
            for (int i = 0; i < 4; ++i) {
                int er = (wr * 4 + i) * 16 + lrow;
                hh[i] = *(const bf16x8*)a_ptr(Ah, er, kt * 32 + kgrp);
                hl[i] = *(const bf16x8*)a_ptr(Al, er, kt * 32 + kgrp);
            }
            bf16x8 wh[4], wl[4];
            #pragma unroll
            for (int j = 0; j < 4; ++j) {
                wh[j] = *(const bf16x8*)(wbh[j] + kt * 512);
                wl[j] = *(const bf16x8*)(wbl[j] + kt * 512);
            }
            __builtin_amdgcn_s_setprio(1);
            #pragma unroll
            for (int j = 0; j < 4; ++j)
                #pragma unroll
                for (int i = 0; i < 4; ++i) {
                    acc[i][j] = __builtin_amdgcn_mfma_f32_16x16x32_bf16(wh[j], hh[i], acc[i][j], 0, 0, 0);
                    acc[i][j] = __builtin_amdgcn_mfma_f32_16x16x32_bf16(wl[j], hh[i], acc[i][j], 0, 0, 0);
                    acc[i][j] = __builtin_amdgcn_mfma_f32_16x16x32_bf16(wh[j], hl[i], acc[i][j], 0, 0, 0);
                }
            __builtin_amdgcn_s_setprio(0);
        }
    }
    __syncthreads();
    #pragma unroll
    for (int j = 0; j < 4; ++j) {
        int nb = (wc * 4 + j) * 16 + (lane >> 4) * 4;
        float4 bv = *(const float4*)&b2[nb];
        #pragma unroll
        for (int i = 0; i < 4; ++i) {
            int e = (wr * 4 + i) * 16 + lrow;
            float v0 = fmaxf(acc[i][j][0] + bv.x, 0.f);
            float v1 = fmaxf(acc[i][j][1] + bv.y, 0.f);
            float v2 = fmaxf(acc[i][j][2] + bv.z, 0.f);
            float v3 = fmaxf(acc[i][j][3] + bv.w, 0.f);
            uint2 hw, lw;
            split_pack4(v0, v1, v2, v3, hw, lw);
            *(uint2*)a_ptr(Ah, e, nb) = hw;
            *(uint2*)a_ptr(Al, e, nb) = lw;
        }
    }
    __syncthreads();

    // ================= layer 3: K=256 (KT=8), 64 features
    // wave w -> e-tile w, all 4 feature tiles
    f32x4 acc3[4];
    #pragma unroll
    for (int q = 0; q < 4; ++q) acc3[q] = zf;
    for (int kt = 0; kt < 8; ++kt) {
        int er = w * 16 + lrow;
        bf16x8 hh = *(const bf16x8*)a_ptr(Ah, er, kt * 32 + kgrp);
        bf16x8 hl = *(const bf16x8*)a_ptr(Al, er, kt * 32 + kgrp);
        __builtin_amdgcn_s_setprio(1);
        #pragma unroll
        for (int q = 0; q < 4; ++q) {
            const size_t fb = ((size_t)(q * 8 + kt) * 64 + lane) * 8;
            bf16x8 wh = *(const bf16x8*)&P3h[fb];
            bf16x8 wl = *(const bf16x8*)&P3l[fb];
            acc3[q] = __builtin_amdgcn_mfma_f32_16x16x32_bf16(wh, hh, acc3[q], 0, 0, 0);
            acc3[q] = __builtin_amdgcn_mfma_f32_16x16x32_bf16(wl, hh, acc3[q], 0, 0, 0);
            acc3[q] = __builtin_amdgcn_mfma_f32_16x16x32_bf16(wh, hl, acc3[q], 0, 0, 0);
        }
        __builtin_amdgcn_s_setprio(0);
    }
    {
        int e = e0 + w * 16 + lrow;
        #pragma unroll
        for (int q = 0; q < 4; ++q) {
            int nb = q * 16 + (lane >> 4) * 4;
            float4 bv = *(const float4*)&b3[nb];
            float4 o;
            o.x = acc3[q][0] + bv.x; o.y = acc3[q][1] + bv.y;
            o.z = acc3[q][2] + bv.z; o.w = acc3[q][3] + bv.w;
            if (e < E) *(float4*)&out[(size_t)e * 64 + nb] = o;
        }
    }
}

// ---------------------------------------------------------------- launcher
extern "C" void kernel_launch(void* const* d_in, const int* in_sizes, int n_in,
                              void* d_out, int out_size, void* d_ws, size_t ws_size,
                              hipStream_t stream) {
    const float* feat = (const float*)d_in[0];
    const int*   ei   = (const int*)d_in[1];
    const float* W1 = (const float*)d_in[3];
    const float* b1 = (const float*)d_in[4];
    const float* W2 = (const float*)d_in[5];
    const float* b2 = (const float*)d_in[6];
    const float* W3 = (const float*)d_in[7];
    const float* b3 = (const float*)d_in[8];
    float* out = (float*)d_out;

    const int E = in_sizes[0] / 64;
    const int N = NNODES;

    char* p = (char*)d_ws;
    u16* T = (u16*)p;                   p += (size_t)N * 256 * 2;
    u16* P1h = (u16*)p;                 p += 81920 * 2;
    u16* P1l = (u16*)p;                 p += 81920 * 2;
    u16* P2h = (u16*)p;                 p += 65536 * 2;
    u16* P2l = (u16*)p;                 p += 65536 * 2;
    u16* P3h = (u16*)p;                 p += 16384 * 2;
    u16* P3l = (u16*)p;                 p += 16384 * 2;
    int* deg = (int*)p;                 p += (size_t)N * 4;
    int* cursor = (int*)p;              p += (size_t)N * 4;
    int* off = (int*)p;                 p += (size_t)(N + 16) * 4;
    int* elist = (int*)p;               p += (size_t)2 * E * 4;

    hipLaunchKernelGGL(csr_init, dim3((N + 255) / 256), dim3(256), 0, stream,
                       deg, cursor, N);
    hipLaunchKernelGGL(count_deg, dim3((2 * E + 255) / 256), dim3(256), 0, stream,
                       ei, deg, 2 * E);
    hipLaunchKernelGGL(scan_deg, dim3(1), dim3(1024), 0, stream, deg, off, N);
    hipLaunchKernelGGL(fill_csr, dim3((2 * E + 255) / 256), dim3(256), 0, stream,
                       ei, off, cursor, elist, E);
    hipLaunchKernelGGL(node_aggregate, dim3((N + 3) / 4), dim3(256), 0, stream,
                       (const float4*)feat, off, elist, T, N);
    hipLaunchKernelGGL(pack_weights, dim3(80), dim3(256), 0, stream,
                       W1, W2, W3, P1h, P1l, P2h, P2l, P3h, P3l);
    hipLaunchKernelGGL(mlp_mfma, dim3((E + MT - 1) / MT), dim3(512), 0, stream,
                       feat, ei, T,
                       P1h, P1l, P2h, P2l, P3h, P3l,
                       b1, b2, b3, out, E);
}

// Round 8
// 1220.451 us; speedup vs baseline: 1.0279x; 1.0279x over previous
//
#include <hip/hip_runtime.h>

// E = 800000, D = 64, N = 50000, MLP 320 -> 256 -> 256 -> 64.
// R7: 2-term split GEMM: y = W*Hh with W = Wh + Wl (exact split), activations
//     RNE-rounded to bf16 (single Ah LDS array). Error budget: activation
//     rounding ~1e-3 rel; measured absmax so far (7.8e-3) is aggregation-order
//     noise, threshold 4.7e-2.
//   - MT=128 @ 512 threads, LDS = 80 KiB -> 2 blocks/CU (R6 tile, R5 occupancy)
//   - layer 3: one feature-tile weight stream per wave (no 8x redundancy)
//   - agg table T[node][2][64] u16 (sumH | mulH), RNE
//   - keeps: W1 linearity fold, CSR aggregation, XOR swizzle, setprio
//
// d_ws: T u16[N*128] | P1h/P1l u16[81920] | P2h/P2l u16[65536] | P3h/P3l u16[16384]
//       | deg int[N] | cursor int[N] | off int[N+16] | elist int[2E]

#define NNODES 50000
#define MT 128

typedef unsigned short u16;
typedef unsigned int u32;
typedef __attribute__((ext_vector_type(8))) short bf16x8;
typedef __attribute__((ext_vector_type(4))) float f32x4;

#define PSEL 0x07060302u   // result = [b.hi16, a.hi16] (a -> low half)

// swizzled H-tile address: element (m, k) of a [128][320] u16 tile
__device__ __forceinline__ void* a_ptr(u16* base, int m, int k) {
    int byte = (m * 320 + k) * 2;
    byte ^= (m & 7) << 4;
    return (char*)base + byte;
}

// RNE-round two floats to bf16, packed into one u32 (a -> low half)
__device__ __forceinline__ u32 rne2(float a, float b) {
    u32 ua = __float_as_uint(a), ub = __float_as_uint(b);
    ua += 0x7FFFu + ((ua >> 16) & 1u);
    ub += 0x7FFFu + ((ub >> 16) & 1u);
    return __builtin_amdgcn_perm(ub, ua, PSEL);
}

__device__ inline void split_rne(float x, u16& hi, u16& lo) {   // cold pack path
    unsigned u = __float_as_uint(x);
    unsigned r = (u + 0x7FFFu + ((u >> 16) & 1u)) >> 16;
    hi = (u16)r;
    float hf = __uint_as_float(r << 16);
    float l = x - hf;
    unsigned ul = __float_as_uint(l);
    unsigned rl = (ul + 0x7FFFu + ((ul >> 16) & 1u)) >> 16;
    lo = (u16)rl;
}

// ---------------------------------------------------------------- CSR build
__global__ __launch_bounds__(256) void csr_init(int* __restrict__ deg,
                                                int* __restrict__ cursor, int n) {
    int t = blockIdx.x * 256 + threadIdx.x;
    if (t < n) { deg[t] = 0; cursor[t] = 0; }
}

__global__ __launch_bounds__(256) void count_deg(const int* __restrict__ ei,
                                                 int* __restrict__ deg, int twoE) {
    int t = blockIdx.x * 256 + threadIdx.x;
    if (t < twoE) atomicAdd(&deg[ei[t]], 1);
}

// single block, 1024 threads: chunked serial + block-scan of partials
__global__ __launch_bounds__(1024) void scan_deg(const int* __restrict__ deg,
                                                 int* __restrict__ off, int n) {
    __shared__ int part[1024];
    int tid = threadIdx.x;
    int chunk = (n + 1023) / 1024;
    int lo = tid * chunk;
    int hi = lo + chunk; if (hi > n) hi = n;
    int s = 0;
    for (int i = lo; i < hi; ++i) s += deg[i];
    part[tid] = s;
    __syncthreads();
    for (int st = 1; st < 1024; st <<= 1) {
        int v = (tid >= st) ? part[tid - st] : 0;
        __syncthreads();
        part[tid] += v;
        __syncthreads();
    }
    int pre = tid ? part[tid - 1] : 0;
    for (int i = lo; i < hi; ++i) { off[i] = pre; pre += deg[i]; }
    if (tid == 1023) off[n] = pre;
}

__global__ __launch_bounds__(256) void fill_csr(const int* __restrict__ ei,
                                                const int* __restrict__ off,
                                                int* __restrict__ cursor,
                                                int* __restrict__ elist,
                                                int E) {
    int t = blockIdx.x * 256 + threadIdx.x;
    if (t >= 2 * E) return;
    int n = ei[t];
    int p = atomicAdd(&cursor[n], 1);
    elist[off[n] + p] = (t < E) ? t : t - E;
}

// one wave per node; writes T[node][2][64] u16: 0 = sumH, 64 = mulH (RNE bf16)
__global__ __launch_bounds__(256) void node_aggregate(
    const float4* __restrict__ feat4, const int* __restrict__ off,
    const int* __restrict__ elist,
    u16* __restrict__ T, int nNodes) {
    int node = blockIdx.x * 4 + (threadIdx.x >> 6);
    if (node >= nNodes) return;
    int lane = threadIdx.x & 63;
    int g = lane >> 4, q = lane & 15;
    int beg = off[node], end = off[node + 1];
    float4 s = make_float4(0.f, 0.f, 0.f, 0.f);
    float4 p = make_float4(1.f, 1.f, 1.f, 1.f);
    for (int i = beg + g; i < end; i += 4) {
        float4 x = feat4[(size_t)elist[i] * 16 + q];
        s.x += x.x; s.y += x.y; s.z += x.z; s.w += x.w;
        p.x *= x.x; p.y *= x.y; p.z *= x.z; p.w *= x.w;
    }
    #pragma unroll
    for (int d = 16; d < 64; d <<= 1) {
        s.x += __shfl_xor(s.x, d); s.y += __shfl_xor(s.y, d);
        s.z += __shfl_xor(s.z, d); s.w += __shfl_xor(s.w, d);
        p.x *= __shfl_xor(p.x, d); p.y *= __shfl_xor(p.y, d);
        p.z *= __shfl_xor(p.z, d); p.w *= __shfl_xor(p.w, d);
    }
    if (g == 0) {
        size_t base = (size_t)node * 128 + q * 4;
        uint2 sv, pv;
        sv.x = rne2(s.x, s.y); sv.y = rne2(s.z, s.w);
        pv.x = rne2(p.x, p.y); pv.y = rne2(p.z, p.w);
        *(uint2*)&T[base]      = sv;
        *(uint2*)&T[base + 64] = pv;
    }
}

// ---------------------------------------------------------------- W pack
// frag = (ct*KT + kt)*64 + lane; lane holds W[ct*16+(lane&15)][kt*32+(lane>>4)*8+j]
// Layer-1 fold: col k<64 -> W1[r][k] - W1[r][64+k] - W1[r][128+k]
__global__ __launch_bounds__(256) void pack_weights(
    const float* __restrict__ W1, const float* __restrict__ W2,
    const float* __restrict__ W3,
    u16* __restrict__ P1h, u16* __restrict__ P1l,
    u16* __restrict__ P2h, u16* __restrict__ P2l,
    u16* __restrict__ P3h, u16* __restrict__ P3l) {
    int t = blockIdx.x * 256 + threadIdx.x;
    const float* W; u16 *Ph, *Pl; int K, frag, fold = 0;
    if (t < 10240)        { W = W1; Ph = P1h; Pl = P1l; K = 320; frag = t; fold = 1; }
    else if (t < 18432)   { W = W2; Ph = P2h; Pl = P2l; K = 256; frag = t - 10240; }
    else if (t < 20480)   { W = W3; Ph = P3h; Pl = P3l; K = 256; frag = t - 18432; }
    else return;
    int KT = K / 32;
    int lane = frag & 63;
    int tile = frag >> 6;
    int kt = tile % KT;
    int ct = tile / KT;
    int row = ct * 16 + (lane & 15);
    int k0 = kt * 32 + (lane >> 4) * 8;
    const float* src = W + (size_t)row * K;
    u16* dh = Ph + (size_t)frag * 8;
    u16* dl = Pl + (size_t)frag * 8;
    #pragma unroll
    for (int j = 0; j < 8; ++j) {
        int k = k0 + j;
        float v = src[k];
        if (fold && k < 64) v -= src[64 + k] + src[128 + k];
        u16 h, l;
        split_rne(v, h, l);
        dh[j] = h; dl[j] = l;
    }
}

// ---------------------------------------------------------------- MFMA MLP
// 512 threads = 8 waves (wr 0..1 x wc 0..3), MT=128 edges (8 e-tiles, 4/wave).
// MFMA(A = W-frag, B = Hh-frag): D col(lane&15) = edge, row = 4 consecutive feats.
__global__ __launch_bounds__(512, 4) void mlp_mfma(
    const float* __restrict__ feat, const int* __restrict__ ei,
    const u16* __restrict__ T,
    const u16* __restrict__ P1h, const u16* __restrict__ P1l,
    const u16* __restrict__ P2h, const u16* __restrict__ P2l,
    const u16* __restrict__ P3h, const u16* __restrict__ P3l,
    const float* __restrict__ b1, const float* __restrict__ b2,
    const float* __restrict__ b3,
    float* __restrict__ out, int E) {
    __shared__ __align__(16) u16 Ah[MT * 320];   // 80 KiB, XOR-swizzled

    const int tid = threadIdx.x;
    const int e0 = blockIdx.x * MT;

    // ---- gather h0 = [feat | Su | Sv | Mu | Mv] (bf16 hi only)
    // 5120 items = 128 edges x 5 sections x 8 octs; 10 items/thread. E%128==0.
    #pragma unroll
    for (int it = 0; it < 10; ++it) {
        int idx = tid + it * 512;
        int r = idx / 40;
        int rem = idx - r * 40;
        int sec = rem >> 3, oct = rem & 7;
        int e = e0 + r;
        int col = sec * 64 + oct * 8;
        uint4 hv;
        if (sec == 0) {
            const float4* f4 = (const float4*)(feat + (size_t)e * 64 + oct * 8);
            float4 a = f4[0], b = f4[1];
            hv.x = rne2(a.x, a.y); hv.y = rne2(a.z, a.w);
            hv.z = rne2(b.x, b.y); hv.w = rne2(b.z, b.w);
        } else {
            int node = ei[(size_t)((sec & 1) ? 0 : E) + e];   // sec 1,3 -> u; 2,4 -> v
            int s = (sec <= 2) ? 0 : 64;                      // sum vs mul
            size_t base = (size_t)node * 128 + s + oct * 8;
            hv = *(const uint4*)(T + base);
        }
        *(uint4*)a_ptr(Ah, r, col) = hv;
    }
    __syncthreads();

    const int lane = tid & 63;
    const int w = tid >> 6;
    const int wr = w >> 2;        // 0..1: e-tiles wr*4 + {0..3}
    const int wc = w & 3;         // 0..3: feature tiles wc*4 + {0..3}
    const int lrow = lane & 15;
    const int kgrp = (lane >> 4) * 8;

    const f32x4 zf = {0.f, 0.f, 0.f, 0.f};
    f32x4 acc[4][4];

    // ================= layer 1: K=320 (KT=10), relu
    #pragma unroll
    for (int i = 0; i < 4; ++i)
        #pragma unroll
        for (int j = 0; j < 4; ++j) acc[i][j] = zf;
    {
        const u16 *wbh[4], *wbl[4];
        #pragma unroll
        for (int j = 0; j < 4; ++j) {
            size_t off = ((size_t)(wc * 4 + j) * 10 * 64 + lane) * 8;
            wbh[j] = P1h + off; wbl[j] = P1l + off;
        }
        for (int kt = 0; kt < 10; ++kt) {
            bf16x8 hh[4];
            #pragma unroll
            for (int i = 0; i < 4; ++i) {
                int er = (wr * 4 + i) * 16 + lrow;
                hh[i] = *(const bf16x8*)a_ptr(Ah, er, kt * 32 + kgrp);
            }
            __builtin_amdgcn_s_setprio(1);
            #pragma unroll
            for (int j = 0; j < 4; ++j) {
                bf16x8 wh = *(const bf16x8*)(wbh[j] + kt * 512);
                bf16x8 wl = *(const bf16x8*)(wbl[j] + kt * 512);
                #pragma unroll
                for (int i = 0; i < 4; ++i) {
                    acc[i][j] = __builtin_amdgcn_mfma_f32_16x16x32_bf16(wh, hh[i], acc[i][j], 0, 0, 0);
                    acc[i][j] = __builtin_amdgcn_mfma_f32_16x16x32_bf16(wl, hh[i], acc[i][j], 0, 0, 0);
                }
            }
            __builtin_amdgcn_s_setprio(0);
        }
    }
    __syncthreads();
    #pragma unroll
    for (int j = 0; j < 4; ++j) {
        int nb = (wc * 4 + j) * 16 + (lane >> 4) * 4;
        float4 bv = *(const float4*)&b1[nb];
        #pragma unroll
        for (int i = 0; i < 4; ++i) {
            int e = (wr * 4 + i) * 16 + lrow;
            float v0 = fmaxf(acc[i][j][0] + bv.x, 0.f);
            float v1 = fmaxf(acc[i][j][1] + bv.y, 0.f);
            float v2 = fmaxf(acc[i][j][2] + bv.z, 0.f);
            float v3 = fmaxf(acc[i][j][3] + bv.w, 0.f);
            uint2 hw;
            hw.x = rne2(v0, v1); hw.y = rne2(v2, v3);
            *(uint2*)a_ptr(Ah, e, nb) = hw;
        }
    }
    __syncthreads();

    // ================= layer 2: K=256 (KT=8), relu
    #pragma unroll
    for (int i = 0; i < 4; ++i)
        #pragma unroll
        for (int j = 0; j < 4; ++j) acc[i][j] = zf;
    {
        const u16 *wbh[4], *wbl[4];
        #pragma unroll
        for (int j = 0; j < 4; ++j) {
            size_t off = ((size_t)(wc * 4 + j) * 8 * 64 + lane) * 8;
            wbh[j] = P2h + off; wbl[j] = P2l + off;
        }
        for (int kt = 0; kt < 8; ++kt) {
            bf16x8 hh[4];
            #pragma unroll
            for (int i = 0; i < 4; ++i) {
                int er = (wr * 4 + i) * 16 + lrow;
                hh[i] = *(const bf16x8*)a_ptr(Ah, er, kt * 32 + kgrp);
            }
            __builtin_amdgcn_s_setprio(1);
            #pragma unroll
            for (int j = 0; j < 4; ++j) {
                bf16x8 wh = *(const bf16x8*)(wbh[j] + kt * 512);
                bf16x8 wl = *(const bf16x8*)(wbl[j] + kt * 512);
                #pragma unroll
                for (int i = 0; i < 4; ++i) {
                    acc[i][j] = __builtin_amdgcn_mfma_f32_16x16x32_bf16(wh, hh[i], acc[i][j], 0, 0, 0);
                    acc[i][j] = __builtin_amdgcn_mfma_f32_16x16x32_bf16(wl, hh[i], acc[i][j], 0, 0, 0);
                }
            }
            __builtin_amdgcn_s_setprio(0);
        }
    }
    __syncthreads();
    #pragma unroll
    for (int j = 0; j < 4; ++j) {
        int nb = (wc * 4 + j) * 16 + (lane >> 4) * 4;
        float4 bv = *(const float4*)&b2[nb];
        #pragma unroll
        for (int i = 0; i < 4; ++i) {
            int e = (wr * 4 + i) * 16 + lrow;
            float v0 = fmaxf(acc[i][j][0] + bv.x, 0.f);
            float v1 = fmaxf(acc[i][j][1] + bv.y, 0.f);
            float v2 = fmaxf(acc[i][j][2] + bv.z, 0.f);
            float v3 = fmaxf(acc[i][j][3] + bv.w, 0.f);
            uint2 hw;
            hw.x = rne2(v0, v1); hw.y = rne2(v2, v3);
            *(uint2*)a_ptr(Ah, e, nb) = hw;
        }
    }
    __syncthreads();

    // ================= layer 3: K=256 (KT=8), 64 features
    // wave w: single feature tile q3 = w&3 (one weight stream), e-tiles
    // et = (w>>2) + 2*t for t = 0..3.
    const int q3 = w & 3;
    const int eb = w >> 2;
    f32x4 acc3[4];
    #pragma unroll
    for (int t = 0; t < 4; ++t) acc3[t] = zf;
    for (int kt = 0; kt < 8; ++kt) {
        const size_t fb = ((size_t)(q3 * 8 + kt) * 64 + lane) * 8;
        bf16x8 wh = *(const bf16x8*)&P3h[fb];
        bf16x8 wl = *(const bf16x8*)&P3l[fb];
        bf16x8 hh[4];
        #pragma unroll
        for (int t = 0; t < 4; ++t) {
            int er = (eb + 2 * t) * 16 + lrow;
            hh[t] = *(const bf16x8*)a_ptr(Ah, er, kt * 32 + kgrp);
        }
        __builtin_amdgcn_s_setprio(1);
        #pragma unroll
        for (int t = 0; t < 4; ++t) {
            acc3[t] = __builtin_amdgcn_mfma_f32_16x16x32_bf16(wh, hh[t], acc3[t], 0, 0, 0);
            acc3[t] = __builtin_amdgcn_mfma_f32_16x16x32_bf16(wl, hh[t], acc3[t], 0, 0, 0);
        }
        __builtin_amdgcn_s_setprio(0);
    }
    {
        int nb = q3 * 16 + (lane >> 4) * 4;
        float4 bv = *(const float4*)&b3[nb];
        #pragma unroll
        for (int t = 0; t < 4; ++t) {
            int e = e0 + (eb + 2 * t) * 16 + lrow;
            float4 o;
            o.x = acc3[t][0] + bv.x; o.y = acc3[t][1] + bv.y;
            o.z = acc3[t][2] + bv.z; o.w = acc3[t][3] + bv.w;
            if (e < E) *(float4*)&out[(size_t)e * 64 + nb] = o;
        }
    }
}

// ---------------------------------------------------------------- launcher
extern "C" void kernel_launch(void* const* d_in, const int* in_sizes, int n_in,
                              void* d_out, int out_size, void* d_ws, size_t ws_size,
                              hipStream_t stream) {
    const float* feat = (const float*)d_in[0];
    const int*   ei   = (const int*)d_in[1];
    const float* W1 = (const float*)d_in[3];
    const float* b1 = (const float*)d_in[4];
    const float* W2 = (const float*)d_in[5];
    const float* b2 = (const float*)d_in[6];
    const float* W3 = (const float*)d_in[7];
    const float* b3 = (const float*)d_in[8];
    float* out = (float*)d_out;

    const int E = in_sizes[0] / 64;
    const int N = NNODES;

    char* p = (char*)d_ws;
    u16* T = (u16*)p;                   p += (size_t)N * 128 * 2;
    u16* P1h = (u16*)p;                 p += 81920 * 2;
    u16* P1l = (u16*)p;                 p += 81920 * 2;
    u16* P2h = (u16*)p;                 p += 65536 * 2;
    u16* P2l = (u16*)p;                 p += 65536 * 2;
    u16* P3h = (u16*)p;                 p += 16384 * 2;
    u16* P3l = (u16*)p;                 p += 16384 * 2;
    int* deg = (int*)p;                 p += (size_t)N * 4;
    int* cursor = (int*)p;              p += (size_t)N * 4;
    int* off = (int*)p;                 p += (size_t)(N + 16) * 4;
    int* elist = (int*)p;               p += (size_t)2 * E * 4;

    hipLaunchKernelGGL(csr_init, dim3((N + 255) / 256), dim3(256), 0, stream,
                       deg, cursor, N);
    hipLaunchKernelGGL(count_deg, dim3((2 * E + 255) / 256), dim3(256), 0, stream,
                       ei, deg, 2 * E);
    hipLaunchKernelGGL(scan_deg, dim3(1), dim3(1024), 0, stream, deg, off, N);
    hipLaunchKernelGGL(fill_csr, dim3((2 * E + 255) / 256), dim3(256), 0, stream,
                       ei, off, cursor, elist, E);
    hipLaunchKernelGGL(node_aggregate, dim3((N + 3) / 4), dim3(256), 0, stream,
                       (const float4*)feat, off, elist, T, N);
    hipLaunchKernelGGL(pack_weights, dim3(80), dim3(256), 0, stream,
                       W1, W2, W3, P1h, P1l, P2h, P2l, P3h, P3l);
    hipLaunchKernelGGL(mlp_mfma, dim3((E + MT - 1) / MT), dim3(512), 0, stream,
                       feat, ei, T,
                       P1h, P1l, P2h, P2l, P3h, P3l,
                       b1, b2, b3, out, E);
}